// Round 3
// baseline (139.186 us; speedup 1.0000x reference)
//
#include <hip/hip_runtime.h>

// NetVLAD: N=16, C=1024, P=1024, K=32. MFMA bf16 for both GEMMs (NT layout).
// Runtime dtype detection (fp32 vs bf16 inputs); fp32 accumulate throughout.
// This rev: BARRIER-FREE GEMM main loops.
//  - k_attn: per-wave private LDS slab (32px strip x 64c chunk), 4x4 register
//    transpose staging, w read fragment-direct from global (pre-converted bf16
//    by k_prep), no s_barrier in the K-loop (same-wave LDS is in-order).
//    Parallel softmax epilogue (all 256 threads).
//  - k_vlad: ZERO LDS. Both MFMA operands fragment-direct from global
//    (attn bf16 uint4; x*rnorm converted in-register). p-split x2 for
//    occupancy; partials combined in k_out.
//  - k_out: per-n block: combine partials, -asum*cent, intra+global norms,
//    scaled write. 4 dispatches total.
#define NB   16
#define CC   1024
#define PP   1024
#define KK   32
#define EPSF 1e-12f
#define XPAD 72   // shorts per LDS row (144B: 16B-aligned rows)

typedef __attribute__((ext_vector_type(8))) short  bf16x8;
typedef __attribute__((ext_vector_type(4))) float  f32x4;

__device__ __forceinline__ float bf2f(unsigned short u) {
    union { unsigned int i; float f; } v; v.i = ((unsigned int)u) << 16; return v.f;
}
__device__ __forceinline__ unsigned short f2bf(float f) {
    union { float f; unsigned int i; } v; v.f = f;
    return (unsigned short)((v.i + 0x7fffu + ((v.i >> 16) & 1u)) >> 16);  // RNE
}

template <typename T> struct IO;
template <> struct IO<float> {
    static __device__ __forceinline__ float ld(const float* p) { return *p; }
    static __device__ __forceinline__ f32x4 ld4(const float* p) { return *(const f32x4*)p; }
};
template <> struct IO<unsigned short> {
    static __device__ __forceinline__ float ld(const unsigned short* p) { return bf2f(*p); }
    static __device__ __forceinline__ f32x4 ld4(const unsigned short* p) {
        const ushort4 u = *(const ushort4*)p;
        f32x4 r; r[0] = bf2f(u.x); r[1] = bf2f(u.y); r[2] = bf2f(u.z); r[3] = bf2f(u.w);
        return r;
    }
};

// ---------------------------------------------------------------------------
// K0 (k_prep): dtype detect + convert w -> bf16 (done once; k_attn then loads
// w fragments directly from global with no per-block conversion).
// grid 32 (one k-row each), block 256.
// ---------------------------------------------------------------------------
__global__ __launch_bounds__(256) void k_prep(const void* __restrict__ xv,
                                              const void* __restrict__ wv,
                                              int* __restrict__ flag,
                                              unsigned short* __restrict__ w_bf) {
    __shared__ int s_bad;
    const int t = threadIdx.x, b = blockIdx.x;
    if (t == 0) s_bad = 0;
    __syncthreads();
    const unsigned short* xu = (const unsigned short*)xv;
    int bad = 0;
    for (int i = t; i < 4096; i += 256)
        if (((xu[i] >> 7) & 0xFFu) > 0x9Fu) bad = 1;
    if (bad) atomicOr(&s_bad, 1);
    __syncthreads();
    const int f = s_bad;
    if (b == 0 && t == 0) flag[0] = f;
    const int c = t * 4;                          // one k-row per block
    ushort4 u;
    if (f) {
        const f32x4 v = *(const f32x4*)((const float*)wv + b * CC + c);
        u.x = f2bf(v[0]); u.y = f2bf(v[1]); u.z = f2bf(v[2]); u.w = f2bf(v[3]);
    } else {
        u = *(const ushort4*)((const unsigned short*)wv + b * CC + c);
    }
    *(ushort4*)&w_bf[b * CC + c] = u;
}

// ---------------------------------------------------------------------------
// K1 (k_attn): grid 512 = (n, 32-px strip), block 256 = 4 waves, each wave a
// private 256-c quarter: 4 chunks of 64c, depth-2 register prefetch, wave-
// private LDS (no barriers in main loop). Epilogue: combine 4 partial accs +
// sumsq, rnorm, parallel softmax, coalesced attn write + asum partial.
// ---------------------------------------------------------------------------
struct AttnSmem {
    unsigned short xt[4][2][32 * XPAD];  // per-wave slab, dbuf, [px][c]
    float lg4[4][32][33];                // per-wave partial logits [px][k]
    float red[4][32];                    // per-wave partial sumsq per px
    float asq[4][32];                    // per-wave partial asum per k
    float rnorm[32];
    unsigned short at[32][34];           // attn bf16 staging [px][k]
};

template <typename T>
__device__ __forceinline__ void attn_body(const T* __restrict__ x,
                                          const unsigned short* __restrict__ w_bf,
                                          float* __restrict__ rnorm_ws,
                                          unsigned short* __restrict__ attn_g,
                                          float* __restrict__ asum_part,
                                          AttnSmem& sm) {
    const int b = blockIdx.x, t = threadIdx.x;
    const int n = b >> 5, strip = b & 31, pbase = strip * 32;
    const int lane = t & 63, wq = t >> 6;        // wq = c-quarter 0..3
    const int quad = lane >> 4, l15 = lane & 15;
    const int pg = (lane & 3) * 4;               // px group (first half)
    const int c4 = (lane >> 2) * 4;              // chunk-local c base (0..60)
    const int cqb = wq * 256;                    // c-quarter base
    const size_t xb = (size_t)n * CC * PP + pbase;

    unsigned short* xt0 = &sm.xt[wq][0][0];
    unsigned short* xt1 = &sm.xt[wq][1][0];

    float ss[8] = {0.f, 0.f, 0.f, 0.f, 0.f, 0.f, 0.f, 0.f};
    f32x4 acc00 = {0.f,0.f,0.f,0.f}, acc01 = {0.f,0.f,0.f,0.f};
    f32x4 acc10 = {0.f,0.f,0.f,0.f}, acc11 = {0.f,0.f,0.f,0.f};

    // depth-2 prefetch: two named register sets (chunks 0 and 1)
    f32x4 ra[8], rb[8];
    #pragma unroll
    for (int i = 0; i < 4; ++i) {
        ra[i]     = IO<T>::ld4(&x[xb + (size_t)(cqb + c4 + i) * PP + pg]);
        ra[4 + i] = IO<T>::ld4(&x[xb + (size_t)(cqb + c4 + i) * PP + pg + 16]);
        rb[i]     = IO<T>::ld4(&x[xb + (size_t)(cqb + 64 + c4 + i) * PP + pg]);
        rb[4 + i] = IO<T>::ld4(&x[xb + (size_t)(cqb + 64 + c4 + i) * PP + pg + 16]);
    }

#define ATTN_STEP(CH, R, XT)                                                      \
    do {                                                                          \
        /* stage: two 4x4 register transposes (px halves), sumsq, b64 stores */   \
        _Pragma("unroll")                                                         \
        for (int h = 0; h < 2; ++h) {                                             \
            _Pragma("unroll")                                                     \
            for (int j = 0; j < 4; ++j) {                                         \
                ushort4 u;                                                        \
                u.x = f2bf(R[4*h+0][j]); u.y = f2bf(R[4*h+1][j]);                 \
                u.z = f2bf(R[4*h+2][j]); u.w = f2bf(R[4*h+3][j]);                 \
                ss[4*h+j] += R[4*h+0][j]*R[4*h+0][j] + R[4*h+1][j]*R[4*h+1][j]    \
                           + R[4*h+2][j]*R[4*h+2][j] + R[4*h+3][j]*R[4*h+3][j];   \
                *(ushort4*)&XT[(pg + 16*h + j) * XPAD + c4] = u;                  \
            }                                                                     \
        }                                                                         \
        if ((CH) + 2 < 4) {                                                       \
            _Pragma("unroll")                                                     \
            for (int i = 0; i < 4; ++i) {                                         \
                R[i]     = IO<T>::ld4(&x[xb + (size_t)(cqb + ((CH)+2)*64 + c4 + i) * PP + pg]);      \
                R[4 + i] = IO<T>::ld4(&x[xb + (size_t)(cqb + ((CH)+2)*64 + c4 + i) * PP + pg + 16]); \
            }                                                                     \
        }                                                                         \
        _Pragma("unroll")                                                         \
        for (int ks = 0; ks < 2; ++ks) {                                          \
            const bf16x8 a0 = *(const bf16x8*)&XT[l15 * XPAD + ks * 32 + quad * 8];        \
            const bf16x8 a1 = *(const bf16x8*)&XT[(16 + l15) * XPAD + ks * 32 + quad * 8]; \
            const int wc = cqb + (CH) * 64 + ks * 32 + quad * 8;                  \
            const bf16x8 b0 = *(const bf16x8*)&w_bf[l15 * CC + wc];               \
            const bf16x8 b1 = *(const bf16x8*)&w_bf[(16 + l15) * CC + wc];        \
            acc00 = __builtin_amdgcn_mfma_f32_16x16x32_bf16(a0, b0, acc00, 0,0,0);\
            acc01 = __builtin_amdgcn_mfma_f32_16x16x32_bf16(a0, b1, acc01, 0,0,0);\
            acc10 = __builtin_amdgcn_mfma_f32_16x16x32_bf16(a1, b0, acc10, 0,0,0);\
            acc11 = __builtin_amdgcn_mfma_f32_16x16x32_bf16(a1, b1, acc11, 0,0,0);\
        }                                                                         \
    } while (0)

    ATTN_STEP(0, ra, xt0);
    ATTN_STEP(1, rb, xt1);
    ATTN_STEP(2, ra, xt0);
    ATTN_STEP(3, rb, xt1);
#undef ATTN_STEP

    // sumsq: reduce over c-lanes (bits 2..5), write per-wave partials
    #pragma unroll
    for (int i = 0; i < 8; ++i) {
        ss[i] += __shfl_xor(ss[i], 4, 64);
        ss[i] += __shfl_xor(ss[i], 8, 64);
        ss[i] += __shfl_xor(ss[i], 16, 64);
        ss[i] += __shfl_xor(ss[i], 32, 64);
    }
    if (lane < 4) {
        #pragma unroll
        for (int h = 0; h < 2; ++h)
            #pragma unroll
            for (int j = 0; j < 4; ++j)
                sm.red[wq][lane * 4 + 16 * h + j] = ss[4 * h + j];
    }
    // partial logits -> lg4 (D row = quad*4+reg, col = l15)
    #pragma unroll
    for (int reg = 0; reg < 4; ++reg) {
        sm.lg4[wq][quad * 4 + reg][l15]           = acc00[reg];
        sm.lg4[wq][quad * 4 + reg][16 + l15]      = acc01[reg];
        sm.lg4[wq][16 + quad * 4 + reg][l15]      = acc10[reg];
        sm.lg4[wq][16 + quad * 4 + reg][16 + l15] = acc11[reg];
    }
    __syncthreads();
    if (t < 32) {
        const float s = sm.red[0][t] + sm.red[1][t] + sm.red[2][t] + sm.red[3][t];
        const float r = 1.0f / fmaxf(sqrtf(s), EPSF);
        sm.rnorm[t] = r;
        rnorm_ws[n * PP + pbase + t] = r;
    }
    __syncthreads();
    {   // parallel softmax: px = t>>3, 4 k's per thread, 8-lane k-reduction
        const int px = t >> 3, kq = (t & 7) * 4;
        const float rn = sm.rnorm[px];
        float v[4]; float mx = -1e30f;
        #pragma unroll
        for (int j = 0; j < 4; ++j) {
            v[j] = (sm.lg4[0][px][kq + j] + sm.lg4[1][px][kq + j]
                  + sm.lg4[2][px][kq + j] + sm.lg4[3][px][kq + j]) * rn;
            mx = fmaxf(mx, v[j]);
        }
        mx = fmaxf(mx, __shfl_xor(mx, 1, 64));
        mx = fmaxf(mx, __shfl_xor(mx, 2, 64));
        mx = fmaxf(mx, __shfl_xor(mx, 4, 64));
        float e[4], s = 0.f;
        #pragma unroll
        for (int j = 0; j < 4; ++j) { e[j] = expf(v[j] - mx); s += e[j]; }
        s += __shfl_xor(s, 1, 64);
        s += __shfl_xor(s, 2, 64);
        s += __shfl_xor(s, 4, 64);
        const float inv = 1.0f / s;
        float as[4];
        #pragma unroll
        for (int j = 0; j < 4; ++j) {
            const unsigned short uu = f2bf(e[j] * inv);
            sm.at[px][kq + j] = uu;
            as[j] = bf2f(uu);
        }
        // per-k partial asum over this wave's 8 px (bits 3..5)
        #pragma unroll
        for (int j = 0; j < 4; ++j) {
            as[j] += __shfl_xor(as[j], 8, 64);
            as[j] += __shfl_xor(as[j], 16, 64);
            as[j] += __shfl_xor(as[j], 32, 64);
        }
        if ((lane >> 3) == 0) {
            #pragma unroll
            for (int j = 0; j < 4; ++j) sm.asq[t >> 6][kq + j] = as[j];
        }
    }
    __syncthreads();
    if (t < 32)
        asum_part[(n * 32 + strip) * KK + t]
            = sm.asq[0][t] + sm.asq[1][t] + sm.asq[2][t] + sm.asq[3][t];
    {   // coalesced attn write: k = t>>3, 4 px per thread
        const int k = t >> 3, p4 = (t & 7) * 4;
        ushort4 uo;
        uo.x = sm.at[p4 + 0][k]; uo.y = sm.at[p4 + 1][k];
        uo.z = sm.at[p4 + 2][k]; uo.w = sm.at[p4 + 3][k];
        *(ushort4*)&attn_g[((size_t)n * KK + k) * PP + pbase + p4] = uo;
    }
}

__global__ __launch_bounds__(256) void k_attn(const void* __restrict__ x,
                                              const unsigned short* __restrict__ w_bf,
                                              const int* __restrict__ flag,
                                              float* __restrict__ rnorm_ws,
                                              unsigned short* __restrict__ attn_g,
                                              float* __restrict__ asum_part) {
    __shared__ AttnSmem sm;
    if (*flag) attn_body<float>((const float*)x, w_bf, rnorm_ws, attn_g, asum_part, sm);
    else       attn_body<unsigned short>((const unsigned short*)x, w_bf, rnorm_ws,
                                         attn_g, asum_part, sm);
}

// ---------------------------------------------------------------------------
// K2 (k_vlad): grid 1024 = (n, 32-c tile, p-half), block 256 = 4 waves
// (mt = k-half, nt = c-half). ZERO LDS, barrier-free: A (attn) and B
// (x*rnorm -> bf16) fragments loaded directly from global; depth-4 pipeline.
// Writes partial acc to vlad_part[ph]; all epilogue math moved to k_out.
// ---------------------------------------------------------------------------
template <typename T>
__device__ __forceinline__ void vlad_body(const T* __restrict__ x,
                                          const float* __restrict__ rnorm_ws,
                                          const unsigned short* __restrict__ attn_g,
                                          float* __restrict__ vlad_part) {
    const int b = blockIdx.x, t = threadIdx.x;
    const int n = b >> 6, rr = b & 63, ct = rr >> 1, ph = rr & 1;
    const int lane = t & 63, wid = t >> 6;
    const int quad = lane >> 4, l15 = lane & 15;
    const int mt = wid & 1, nt = wid >> 1;
    const int cbase = ct * 32, pb = ph * 512;
    const int krow = mt * 16 + l15;
    const int crow = cbase + nt * 16 + l15;
    const unsigned short* ap = attn_g + ((size_t)n * KK + krow) * PP + pb + quad * 8;
    const T* xp = x + (size_t)n * CC * PP + (size_t)crow * PP + pb + quad * 8;
    const float* rp = rnorm_ws + n * PP + pb + quad * 8;

    f32x4 acc = {0.f, 0.f, 0.f, 0.f};
    bf16x8 avA, avB, avC, avD;
    f32x4 x0A, x1A, x0B, x1B, x0C, x1C, x0D, x1D;
    f32x4 r0A, r1A, r0B, r1B, r0C, r1C, r0D, r1D;
    avA = *(const bf16x8*)&ap[0];  x0A = IO<T>::ld4(&xp[0]);  x1A = IO<T>::ld4(&xp[4]);
    r0A = *(const f32x4*)&rp[0];   r1A = *(const f32x4*)&rp[4];
    avB = *(const bf16x8*)&ap[32]; x0B = IO<T>::ld4(&xp[32]); x1B = IO<T>::ld4(&xp[36]);
    r0B = *(const f32x4*)&rp[32];  r1B = *(const f32x4*)&rp[36];
    avC = *(const bf16x8*)&ap[64]; x0C = IO<T>::ld4(&xp[64]); x1C = IO<T>::ld4(&xp[68]);
    r0C = *(const f32x4*)&rp[64];  r1C = *(const f32x4*)&rp[68];
    avD = *(const bf16x8*)&ap[96]; x0D = IO<T>::ld4(&xp[96]); x1D = IO<T>::ld4(&xp[100]);
    r0D = *(const f32x4*)&rp[96];  r1D = *(const f32x4*)&rp[100];

#define VSTEP(ST, AV, X0, X1, R0, R1)                                             \
    do {                                                                          \
        bf16x8 bv;                                                                \
        bv[0] = (short)f2bf(X0[0] * R0[0]); bv[1] = (short)f2bf(X0[1] * R0[1]);   \
        bv[2] = (short)f2bf(X0[2] * R0[2]); bv[3] = (short)f2bf(X0[3] * R0[3]);   \
        bv[4] = (short)f2bf(X1[0] * R1[0]); bv[5] = (short)f2bf(X1[1] * R1[1]);   \
        bv[6] = (short)f2bf(X1[2] * R1[2]); bv[7] = (short)f2bf(X1[3] * R1[3]);   \
        acc = __builtin_amdgcn_mfma_f32_16x16x32_bf16(AV, bv, acc, 0, 0, 0);      \
        if ((ST) + 4 < 16) {                                                      \
            const int o = ((ST) + 4) * 32;                                        \
            AV = *(const bf16x8*)&ap[o];                                          \
            X0 = IO<T>::ld4(&xp[o]); X1 = IO<T>::ld4(&xp[o + 4]);                 \
            R0 = *(const f32x4*)&rp[o]; R1 = *(const f32x4*)&rp[o + 4];           \
        }                                                                         \
    } while (0)

    VSTEP(0,  avA, x0A, x1A, r0A, r1A);
    VSTEP(1,  avB, x0B, x1B, r0B, r1B);
    VSTEP(2,  avC, x0C, x1C, r0C, r1C);
    VSTEP(3,  avD, x0D, x1D, r0D, r1D);
    VSTEP(4,  avA, x0A, x1A, r0A, r1A);
    VSTEP(5,  avB, x0B, x1B, r0B, r1B);
    VSTEP(6,  avC, x0C, x1C, r0C, r1C);
    VSTEP(7,  avD, x0D, x1D, r0D, r1D);
    VSTEP(8,  avA, x0A, x1A, r0A, r1A);
    VSTEP(9,  avB, x0B, x1B, r0B, r1B);
    VSTEP(10, avC, x0C, x1C, r0C, r1C);
    VSTEP(11, avD, x0D, x1D, r0D, r1D);
    VSTEP(12, avA, x0A, x1A, r0A, r1A);
    VSTEP(13, avB, x0B, x1B, r0B, r1B);
    VSTEP(14, avC, x0C, x1C, r0C, r1C);
    VSTEP(15, avD, x0D, x1D, r0D, r1D);
#undef VSTEP

    float* vp = vlad_part + (((size_t)ph * NB + n) * KK) * CC;
    const int kk = mt * 16 + quad * 4;
    #pragma unroll
    for (int reg = 0; reg < 4; ++reg)
        vp[(size_t)(kk + reg) * CC + crow] = acc[reg];
}

__global__ __launch_bounds__(256) void k_vlad(const void* __restrict__ x,
                                              const int* __restrict__ flag,
                                              const float* __restrict__ rnorm_ws,
                                              const unsigned short* __restrict__ attn_g,
                                              float* __restrict__ vlad_part) {
    if (*flag) vlad_body<float>((const float*)x, rnorm_ws, attn_g, vlad_part);
    else       vlad_body<unsigned short>((const unsigned short*)x, rnorm_ws, attn_g,
                                         vlad_part);
}

// ---------------------------------------------------------------------------
// K3 (k_out): grid 16 (per n), block 1024 (32 threads per k). Combine the two
// p-half partials, subtract asum*cent, intra-cluster + global norms, scaled
// write (two L2-hot passes, no value storage).
// ---------------------------------------------------------------------------
struct OutSmem { float asum[KK]; float ssq[KK]; float rint[KK]; float rg; };

__global__ __launch_bounds__(1024) void k_out(const float* __restrict__ vlad_part,
                                              const float* __restrict__ asum_part,
                                              const void* __restrict__ cent,
                                              const int* __restrict__ flag,
                                              void* __restrict__ out) {
    __shared__ OutSmem sm;
    const int n = blockIdx.x, t = threadIdx.x;
    if (t < KK) {
        float s = 0.f;
        #pragma unroll
        for (int st = 0; st < 32; ++st) s += asum_part[(n * 32 + st) * KK + t];
        sm.asum[t] = s;
    }
    __syncthreads();
    const int k = t >> 5, l32 = t & 31;
    const float A = sm.asum[k];
    const int isf = *flag;
    const float* p0 = vlad_part + ((size_t)n * KK + k) * CC;
    const float* p1 = vlad_part + ((size_t)(NB + n) * KK + k) * CC;
    float ssq = 0.f;
    #pragma unroll
    for (int j = 0; j < 8; ++j) {
        const int c = l32 * 4 + j * 128;
        const f32x4 v0 = *(const f32x4*)&p0[c];
        const f32x4 v1 = *(const f32x4*)&p1[c];
        f32x4 ce;
        if (isf) ce = *(const f32x4*)((const float*)cent + k * CC + c);
        else {
            const ushort4 u = *(const ushort4*)((const unsigned short*)cent + k * CC + c);
            ce[0] = bf2f(u.x); ce[1] = bf2f(u.y); ce[2] = bf2f(u.z); ce[3] = bf2f(u.w);
        }
        #pragma unroll
        for (int i = 0; i < 4; ++i) {
            const float v = v0[i] + v1[i] - A * ce[i];
            ssq += v * v;
        }
    }
    ssq += __shfl_xor(ssq, 1, 64);
    ssq += __shfl_xor(ssq, 2, 64);
    ssq += __shfl_xor(ssq, 4, 64);
    ssq += __shfl_xor(ssq, 8, 64);
    ssq += __shfl_xor(ssq, 16, 64);
    if (l32 == 0) sm.ssq[k] = ssq;
    __syncthreads();
    if (t < KK) {
        const float s = sm.ssq[t];
        const float r = 1.0f / fmaxf(sqrtf(s), EPSF);
        sm.rint[t] = r;
        float g = s * r * r;
        g += __shfl_xor(g, 1, 64);
        g += __shfl_xor(g, 2, 64);
        g += __shfl_xor(g, 4, 64);
        g += __shfl_xor(g, 8, 64);
        g += __shfl_xor(g, 16, 64);
        if (t == 0) sm.rg = 1.0f / fmaxf(sqrtf(g), EPSF);
    }
    __syncthreads();
    const float f = sm.rint[k] * sm.rg;
    #pragma unroll
    for (int j = 0; j < 8; ++j) {
        const int c = l32 * 4 + j * 128;
        const f32x4 v0 = *(const f32x4*)&p0[c];
        const f32x4 v1 = *(const f32x4*)&p1[c];
        f32x4 ce;
        if (isf) ce = *(const f32x4*)((const float*)cent + k * CC + c);
        else {
            const ushort4 u = *(const ushort4*)((const unsigned short*)cent + k * CC + c);
            ce[0] = bf2f(u.x); ce[1] = bf2f(u.y); ce[2] = bf2f(u.z); ce[3] = bf2f(u.w);
        }
        const size_t ob = ((size_t)n * KK + k) * CC + c;
        if (isf) {
            float4 o;
            o.x = (v0[0] + v1[0] - A * ce[0]) * f;
            o.y = (v0[1] + v1[1] - A * ce[1]) * f;
            o.z = (v0[2] + v1[2] - A * ce[2]) * f;
            o.w = (v0[3] + v1[3] - A * ce[3]) * f;
            *(float4*)((float*)out + ob) = o;
        } else {
            ushort4 u;
            u.x = f2bf((v0[0] + v1[0] - A * ce[0]) * f);
            u.y = f2bf((v0[1] + v1[1] - A * ce[1]) * f);
            u.z = f2bf((v0[2] + v1[2] - A * ce[2]) * f);
            u.w = f2bf((v0[3] + v1[3] - A * ce[3]) * f);
            *(ushort4*)((unsigned short*)out + ob) = u;
        }
    }
}

extern "C" void kernel_launch(void* const* d_in, const int* in_sizes, int n_in,
                              void* d_out, int out_size, void* d_ws, size_t ws_size,
                              hipStream_t stream) {
    const void* x    = d_in[0];
    const void* w    = d_in[1];
    const void* cent = d_in[2];

    float* ws        = (float*)d_ws;
    float* vlad_part = ws;                                   // 2*NB*KK*CC = 1048576 fl
    float* rnorm_ws  = vlad_part + 2 * NB * KK * CC;         // 16384 fl
    float* asum_part = rnorm_ws + NB * PP;                   // NB*32*KK = 16384 fl
    int*   flag      = (int*)(asum_part + NB * 32 * KK);     // 4 ints (16B)
    unsigned short* w_bf   = (unsigned short*)(flag + 4);    // KK*CC = 32768 sh
    unsigned short* attn_g = w_bf + KK * CC;                 // NB*KK*PP = 524288 sh

    k_prep<<<KK, 256, 0, stream>>>(x, w, flag, w_bf);
    k_attn<<<NB * 32, 256, 0, stream>>>(x, w_bf, flag, rnorm_ws, attn_g, asum_part);
    k_vlad<<<NB * 64, 256, 0, stream>>>(x, flag, rnorm_ws, attn_g, vlad_part);
    k_out<<<NB, 1024, 0, stream>>>(vlad_part, asum_part, cent, flag, d_out);
}